// Round 6
// baseline (6354.066 us; speedup 1.0000x reference)
//
#include <hip/hip_runtime.h>

#define HID 100
#define TT  1024
#define BPW 4     // batches per workgroup (4*64 = 256 exactly)
#define WPL 64    // workgroups per LSTM -> grid 192
#define NTHR 512
#define WPAD 97   // W row stride in LDS: (97r+k)%32=(r+k)%32 -> 2-way, free
#define KLDS 96   // k<96 streamed from LDS; k=96..99 in a resident quad

typedef float f32x4 __attribute__((ext_vector_type(4)));

__device__ __forceinline__ float sigf(float x) { return 1.f / (1.f + __expf(-x)); }
__device__ __forceinline__ float tanhf_fast(float x) { return 2.f / (1.f + __expf(-2.f * x)) - 1.f; }
__device__ __forceinline__ float rlane(float v, int l) {
    return __uint_as_float(__builtin_amdgcn_readlane(__float_as_uint(v), l));
}

// v5-OP: outer-product form. lane = gate row (waves 0-6 cover 400 rows),
// W_hh streamed from LDS (staged once, pad-97 -> conflict-free), h broadcast
// via v_readlane from lane-distributed regs, x via wave-uniform s_load.
// Per-thread live state ~40 VGPRs -> nothing for the allocator to spill.
__global__ __launch_bounds__(NTHR, 2) void lstm3_kernel(
    const float* __restrict__ x1, const float* __restrict__ x2, const float* __restrict__ x3,
    const float* __restrict__ Wih1, const float* __restrict__ Whh1, const float* __restrict__ bi1, const float* __restrict__ bh1,
    const float* __restrict__ Wih2, const float* __restrict__ Whh2, const float* __restrict__ bi2, const float* __restrict__ bh2,
    const float* __restrict__ Wih3, const float* __restrict__ Whh3, const float* __restrict__ bi3, const float* __restrict__ bh3,
    float* __restrict__ hws)
{
    const int wg    = blockIdx.x;
    const int L     = wg / WPL;
    const int bbase = (wg % WPL) * BPW;
    const int tid   = threadIdx.x;

    const float* x   = (L == 0) ? x1   : (L == 1) ? x2   : x3;
    const float* Wih = (L == 0) ? Wih1 : (L == 1) ? Wih2 : Wih3;
    const float* Whh = (L == 0) ? Whh1 : (L == 1) ? Whh2 : Whh3;
    const float* bi  = (L == 0) ? bi1  : (L == 1) ? bi2  : bi3;
    const float* bh  = (L == 0) ? bh1  : (L == 1) ? bh2  : bh3;

    __shared__ float wlds[400 * WPAD];          // 155,200 B
    __shared__ float h_lds[BPW][HID];           // 1,600 B (single buffer is safe:
                                                // gate phase reads h into regs first)
    __shared__ float g_lds[BPW][4][HID];        // 6,400 B   -> total 163,200 B

    // ---- one-time W_hh staging (k<96) ----
    for (int i = tid; i < 400 * KLDS; i += NTHR) {
        const int r = i / KLDS, k = i % KLDS;
        wlds[r * WPAD + k] = Whh[r * HID + k];
    }
    for (int i = tid; i < BPW * HID; i += NTHR) ((float*)h_lds)[i] = 0.f;

    const int  wave = tid >> 6, lane = tid & 63;
    const int  rowv = wave * 64 + lane;          // gate row (waves 0..6)
    const bool gact = rowv < 400;
    const int  rowc = min(rowv, 399);
    const int  gslot = rowc / 100, gcell = rowc % 100;
    const float* wrow = &wlds[rowc * WPAD];

    // resident tail quad W[row][96..99] + x-projection row + bias
    const f32x4 W96 = *(const f32x4*)(Whh + (size_t)rowc * HID + 96);
    const f32x4 wi  = *(const f32x4*)(Wih + (size_t)rowc * 4);
    const float bias = bi[rowc] + bh[rowc];

    // update job: all 8 waves, lanes 0..49 -> 400 jobs
    const bool uact = lane < 50;
    const int  uj   = wave * 50 + min(lane, 49);
    const int  ub   = uj / 100, un = uj % 100;
    float cc = 0.f, hh = 0.f;

    // x prefetch for step 0 (wave-uniform addresses -> scalar loads)
    f32x4 xs0 = *(const f32x4*)(x + ((size_t)(bbase + 0) * TT + 0) * 4);
    f32x4 xs1 = *(const f32x4*)(x + ((size_t)(bbase + 1) * TT + 0) * 4);
    f32x4 xs2 = *(const f32x4*)(x + ((size_t)(bbase + 2) * TT + 0) * 4);
    f32x4 xs3 = *(const f32x4*)(x + ((size_t)(bbase + 3) * TT + 0) * 4);

    __syncthreads();

#define GKA(K) do { const float wv = wrow[(K)];                         \
        a0 += rlane(hA0, (K)) * wv; a1 += rlane(hA1, (K)) * wv;         \
        a2 += rlane(hA2, (K)) * wv; a3 += rlane(hA3, (K)) * wv; } while (0)
#define GKB(K) do { const float wv = wrow[(K)];                         \
        a0 += rlane(hB0, (K)-64) * wv; a1 += rlane(hB1, (K)-64) * wv;   \
        a2 += rlane(hB2, (K)-64) * wv; a3 += rlane(hB3, (K)-64) * wv; } while (0)
#define GKR(K, WC) do { const float wv = (WC);                          \
        a0 += rlane(hB0, (K)-64) * wv; a1 += rlane(hB1, (K)-64) * wv;   \
        a2 += rlane(hB2, (K)-64) * wv; a3 += rlane(hB3, (K)-64) * wv; } while (0)

#pragma unroll 1
    for (int st = 0; st < TT; ++st) {
        if (wave < 7) {
            // lane-distributed h: lane l holds h[b][l] and h[b][64+l]
            const int bidx = min(64 + lane, HID - 1);
            const float hA0 = h_lds[0][lane], hB0 = h_lds[0][bidx];
            const float hA1 = h_lds[1][lane], hB1 = h_lds[1][bidx];
            const float hA2 = h_lds[2][lane], hB2 = h_lds[2][bidx];
            const float hA3 = h_lds[3][lane], hB3 = h_lds[3][bidx];

            float a0 = bias + wi.x * xs0.x + wi.y * xs0.y + wi.z * xs0.z + wi.w * xs0.w;
            float a1 = bias + wi.x * xs1.x + wi.y * xs1.y + wi.z * xs1.z + wi.w * xs1.w;
            float a2 = bias + wi.x * xs2.x + wi.y * xs2.y + wi.z * xs2.z + wi.w * xs2.w;
            float a3 = bias + wi.x * xs3.x + wi.y * xs3.y + wi.z * xs3.z + wi.w * xs3.w;

            // prefetch next step's x (covered by ~900 instrs below)
            {
                const int nst = (st < TT - 1) ? st + 1 : st;
                xs0 = *(const f32x4*)(x + ((size_t)(bbase + 0) * TT + nst) * 4);
                xs1 = *(const f32x4*)(x + ((size_t)(bbase + 1) * TT + nst) * 4);
                xs2 = *(const f32x4*)(x + ((size_t)(bbase + 2) * TT + nst) * 4);
                xs3 = *(const f32x4*)(x + ((size_t)(bbase + 3) * TT + nst) * 4);
            }

            GKA(0);  GKA(1);  GKA(2);  GKA(3);  GKA(4);  GKA(5);  GKA(6);  GKA(7);
            GKA(8);  GKA(9);  GKA(10); GKA(11); GKA(12); GKA(13); GKA(14); GKA(15);
            GKA(16); GKA(17); GKA(18); GKA(19); GKA(20); GKA(21); GKA(22); GKA(23);
            GKA(24); GKA(25); GKA(26); GKA(27); GKA(28); GKA(29); GKA(30); GKA(31);
            GKA(32); GKA(33); GKA(34); GKA(35); GKA(36); GKA(37); GKA(38); GKA(39);
            GKA(40); GKA(41); GKA(42); GKA(43); GKA(44); GKA(45); GKA(46); GKA(47);
            GKA(48); GKA(49); GKA(50); GKA(51); GKA(52); GKA(53); GKA(54); GKA(55);
            GKA(56); GKA(57); GKA(58); GKA(59); GKA(60); GKA(61); GKA(62); GKA(63);
            GKB(64); GKB(65); GKB(66); GKB(67); GKB(68); GKB(69); GKB(70); GKB(71);
            GKB(72); GKB(73); GKB(74); GKB(75); GKB(76); GKB(77); GKB(78); GKB(79);
            GKB(80); GKB(81); GKB(82); GKB(83); GKB(84); GKB(85); GKB(86); GKB(87);
            GKB(88); GKB(89); GKB(90); GKB(91); GKB(92); GKB(93); GKB(94); GKB(95);
            GKR(96, W96.x); GKR(97, W96.y); GKR(98, W96.z); GKR(99, W96.w);

            if (gact) {
                g_lds[0][gslot][gcell] = a0;
                g_lds[1][gslot][gcell] = a1;
                g_lds[2][gslot][gcell] = a2;
                g_lds[3][gslot][gcell] = a3;
            }
        }
        __syncthreads();

        if (uact) {
            const float gi = g_lds[ub][0][un];
            const float gf = g_lds[ub][1][un];
            const float gg = g_lds[ub][2][un];
            const float go = g_lds[ub][3][un];
            cc = sigf(gf) * cc + sigf(gi) * tanhf_fast(gg);
            hh = sigf(go) * tanhf_fast(cc);
            h_lds[ub][un] = hh;
        }
        __syncthreads();
    }
#undef GKA
#undef GKB
#undef GKR

    if (uact) hws[(size_t)(bbase + ub) * 300 + L * HID + un] = hh;
}

// out[b][o] = relu(fc_b[o] + sum_j h[b][j] * fc_W[o][j]),  j < 300, o < 12
__global__ __launch_bounds__(64, 1) void fc_kernel(
    const float* __restrict__ hws, const float* __restrict__ fcW,
    const float* __restrict__ fcb, float* __restrict__ out)
{
    const int b = blockIdx.x, lane = threadIdx.x;
    float hv[5];
#pragma unroll
    for (int c = 0; c < 5; c++) {
        const int j = lane + 64 * c;
        hv[c] = (j < 300) ? hws[b * 300 + j] : 0.f;
    }
#pragma unroll
    for (int o = 0; o < 12; o++) {
        float a = 0.f;
#pragma unroll
        for (int c = 0; c < 5; c++) {
            const int j = lane + 64 * c;
            const float wv = (j < 300) ? fcW[o * 300 + j] : 0.f;
            a += hv[c] * wv;
        }
#pragma unroll
        for (int off = 32; off > 0; off >>= 1) a += __shfl_xor(a, off, 64);
        if (lane == 0) out[b * 12 + o] = fmaxf(a + fcb[o], 0.f);
    }
}

extern "C" void kernel_launch(void* const* d_in, const int* in_sizes, int n_in,
                              void* d_out, int out_size, void* d_ws, size_t ws_size,
                              hipStream_t stream)
{
    const float* x1   = (const float*)d_in[0];
    const float* x2   = (const float*)d_in[1];
    const float* x3   = (const float*)d_in[2];
    const float* Wih1 = (const float*)d_in[3];
    const float* Whh1 = (const float*)d_in[4];
    const float* bi1  = (const float*)d_in[5];
    const float* bh1  = (const float*)d_in[6];
    const float* Wih2 = (const float*)d_in[7];
    const float* Whh2 = (const float*)d_in[8];
    const float* bi2  = (const float*)d_in[9];
    const float* bh2  = (const float*)d_in[10];
    const float* Wih3 = (const float*)d_in[11];
    const float* Whh3 = (const float*)d_in[12];
    const float* bi3  = (const float*)d_in[13];
    const float* bh3  = (const float*)d_in[14];
    const float* fcW  = (const float*)d_in[15];
    const float* fcb  = (const float*)d_in[16];

    float* hws = (float*)d_ws;  // 256*300 floats = 300 KiB

    lstm3_kernel<<<3 * WPL, NTHR, 0, stream>>>(x1, x2, x3,
                                               Wih1, Whh1, bi1, bh1,
                                               Wih2, Whh2, bi2, bh2,
                                               Wih3, Whh3, bi3, bh3, hws);
    fc_kernel<<<256, 64, 0, stream>>>(hws, fcW, fcb, (float*)d_out);
}

// Round 7
// 6129.932 us; speedup vs baseline: 1.0366x; 1.0366x over previous
//
#include <hip/hip_runtime.h>

#define HID 100
#define TT  1024
#define BPW 4     // batches per workgroup (4*64 = 256 exactly)
#define WPL 64    // workgroups per LSTM -> grid 192, 1 WG/CU
#define NTHR 512

typedef float f32x4 __attribute__((ext_vector_type(4)));

__device__ __forceinline__ float sigf(float x) { return 1.f / (1.f + __expf(-x)); }
__device__ __forceinline__ float tanhf_fast(float x) { return 2.f / (1.f + __expf(-2.f * x)) - 1.f; }
__device__ __forceinline__ float rlane(float v, int l) {
    return __uint_as_float(__builtin_amdgcn_readlane(__float_as_uint(v), l));
}

// R4 structure (verified correct) + amdgpu_waves_per_eu(2,2).
// R2-R4 post-mortem: the backend's occupancy heuristic (default target) made
// the scheduler sink/rematerialize the 100 weight loads into the loop
// (VGPR_Count 64-88), turning the K-loop into an L2/scratch-bound stream.
// Capping waves/EU at 2 sets the allocator budget to 256 VGPR/thread ->
// holding W resident is free, loads stay hoisted.
// h broadcast: register file via v_readlane (SGPR operand feeds v_fmac
// directly) -> no LDS return-bus wall (R3's 6400 cyc/step limiter).
__global__ __attribute__((amdgpu_waves_per_eu(2, 2)))
__launch_bounds__(NTHR) void lstm3_kernel(
    const float* __restrict__ x1, const float* __restrict__ x2, const float* __restrict__ x3,
    const float* __restrict__ Wih1, const float* __restrict__ Whh1, const float* __restrict__ bi1, const float* __restrict__ bh1,
    const float* __restrict__ Wih2, const float* __restrict__ Whh2, const float* __restrict__ bi2, const float* __restrict__ bh2,
    const float* __restrict__ Wih3, const float* __restrict__ Whh3, const float* __restrict__ bi3, const float* __restrict__ bh3,
    float* __restrict__ hws)
{
    const int wg    = blockIdx.x;
    const int L     = wg / WPL;
    const int bbase = (wg % WPL) * BPW;
    const int tid   = threadIdx.x;

    const float* x   = (L == 0) ? x1   : (L == 1) ? x2   : x3;
    const float* Wih = (L == 0) ? Wih1 : (L == 1) ? Wih2 : Wih3;
    const float* Whh = (L == 0) ? Whh1 : (L == 1) ? Whh2 : Whh3;
    const float* bi  = (L == 0) ? bi1  : (L == 1) ? bi2  : bi3;
    const float* bh  = (L == 0) ? bh1  : (L == 1) ? bh2  : bh3;

    __shared__ __align__(16) float x_lds[BPW][TT][4];   // 64 KiB
    __shared__ __align__(16) float h_lds[2][BPW][HID];  // double-buffered h
    __shared__ __align__(16) float g_lds[BPW][4][HID];  // gates, slot-major

    for (int i = tid; i < BPW * TT; i += NTHR) {
        const int b = i / TT, t = i % TT;
        ((f32x4*)x_lds)[i] = *(const f32x4*)(x + ((size_t)(bbase + b) * TT + t) * 4);
    }
    for (int i = tid; i < BPW * HID; i += NTHR) ((float*)h_lds[0])[i] = 0.f;

    const int  wave = tid >> 6, lane = tid & 63;
    const bool gth  = lane < 50;
    const int  row  = wave * 50 + lane;          // valid if gth
    const int  rowc = wave * 50 + min(lane, 49);
    const int  slot = row / 100;                 // gate slot / update batch
    const int  cell = row % 100;

    // W_hh row: 25 quads in registers (resident under waves_per_eu(2,2))
    const f32x4* wp = (const f32x4*)(Whh + (size_t)rowc * HID);
    f32x4 W0  = wp[0],  W1  = wp[1],  W2  = wp[2],  W3  = wp[3],  W4  = wp[4];
    f32x4 W5  = wp[5],  W6  = wp[6],  W7  = wp[7],  W8  = wp[8],  W9  = wp[9];
    f32x4 W10 = wp[10], W11 = wp[11], W12 = wp[12], W13 = wp[13], W14 = wp[14];
    f32x4 W15 = wp[15], W16 = wp[16], W17 = wp[17], W18 = wp[18], W19 = wp[19];
    f32x4 W20 = wp[20], W21 = wp[21], W22 = wp[22], W23 = wp[23], W24 = wp[24];

    f32x4 wi   = *(const f32x4*)(Wih + (size_t)rowc * 4);
    float bias = bi[rowc] + bh[rowc];

    asm volatile("" : "+v"(W0),  "+v"(W1),  "+v"(W2),  "+v"(W3),  "+v"(W4));
    asm volatile("" : "+v"(W5),  "+v"(W6),  "+v"(W7),  "+v"(W8),  "+v"(W9));
    asm volatile("" : "+v"(W10), "+v"(W11), "+v"(W12), "+v"(W13), "+v"(W14));
    asm volatile("" : "+v"(W15), "+v"(W16), "+v"(W17), "+v"(W18), "+v"(W19));
    asm volatile("" : "+v"(W20), "+v"(W21), "+v"(W22), "+v"(W23), "+v"(W24));

    float cc = 0.f, hh = 0.f;   // state of update job (batch=slot, cell)

    const int gidx1 = min(64 + lane, HID - 1);   // clamped index for h[64+lane]

    __syncthreads();

    // GQ: one weight quad (k = base..base+3) x 4 batches; h via readlane->SGPR.
#define GQ(WV, IDX, LB) do {                                                          \
        { const float s0 = rlane(hr##IDX##_0, (LB)+0), s1 = rlane(hr##IDX##_1, (LB)+0), \
                      s2 = rlane(hr##IDX##_2, (LB)+0), s3 = rlane(hr##IDX##_3, (LB)+0); \
          a0 += s0 * WV.x; a1 += s1 * WV.x; a2 += s2 * WV.x; a3 += s3 * WV.x; }        \
        { const float s0 = rlane(hr##IDX##_0, (LB)+1), s1 = rlane(hr##IDX##_1, (LB)+1), \
                      s2 = rlane(hr##IDX##_2, (LB)+1), s3 = rlane(hr##IDX##_3, (LB)+1); \
          a0 += s0 * WV.y; a1 += s1 * WV.y; a2 += s2 * WV.y; a3 += s3 * WV.y; }        \
        { const float s0 = rlane(hr##IDX##_0, (LB)+2), s1 = rlane(hr##IDX##_1, (LB)+2), \
                      s2 = rlane(hr##IDX##_2, (LB)+2), s3 = rlane(hr##IDX##_3, (LB)+2); \
          a0 += s0 * WV.z; a1 += s1 * WV.z; a2 += s2 * WV.z; a3 += s3 * WV.z; }        \
        { const float s0 = rlane(hr##IDX##_0, (LB)+3), s1 = rlane(hr##IDX##_1, (LB)+3), \
                      s2 = rlane(hr##IDX##_2, (LB)+3), s3 = rlane(hr##IDX##_3, (LB)+3); \
          a0 += s0 * WV.w; a1 += s1 * WV.w; a2 += s2 * WV.w; a3 += s3 * WV.w; }        \
    } while (0)

#pragma unroll 1
    for (int st = 0; st < TT; ++st) {
        const int cur = st & 1;

        // gather h lane-distributed: lane l holds h[b][l] and h[b][64+l]
        const float hr0_0 = h_lds[cur][0][lane], hr1_0 = h_lds[cur][0][gidx1];
        const float hr0_1 = h_lds[cur][1][lane], hr1_1 = h_lds[cur][1][gidx1];
        const float hr0_2 = h_lds[cur][2][lane], hr1_2 = h_lds[cur][2][gidx1];
        const float hr0_3 = h_lds[cur][3][lane], hr1_3 = h_lds[cur][3][gidx1];

        const f32x4 xb0 = *(const f32x4*)&x_lds[0][st][0];
        const f32x4 xb1 = *(const f32x4*)&x_lds[1][st][0];
        const f32x4 xb2 = *(const f32x4*)&x_lds[2][st][0];
        const f32x4 xb3 = *(const f32x4*)&x_lds[3][st][0];
        float a0 = bias + wi.x * xb0.x + wi.y * xb0.y + wi.z * xb0.z + wi.w * xb0.w;
        float a1 = bias + wi.x * xb1.x + wi.y * xb1.y + wi.z * xb1.z + wi.w * xb1.w;
        float a2 = bias + wi.x * xb2.x + wi.y * xb2.y + wi.z * xb2.z + wi.w * xb2.w;
        float a3 = bias + wi.x * xb3.x + wi.y * xb3.y + wi.z * xb3.z + wi.w * xb3.w;

        // k = 0..63 from hr0_*, k = 64..99 from hr1_* (lanes 0..35)
        GQ(W0,  0, 0);  GQ(W1,  0, 4);  GQ(W2,  0, 8);  GQ(W3,  0, 12);
        GQ(W4,  0, 16); GQ(W5,  0, 20); GQ(W6,  0, 24); GQ(W7,  0, 28);
        GQ(W8,  0, 32); GQ(W9,  0, 36); GQ(W10, 0, 40); GQ(W11, 0, 44);
        GQ(W12, 0, 48); GQ(W13, 0, 52); GQ(W14, 0, 56); GQ(W15, 0, 60);
        GQ(W16, 1, 0);  GQ(W17, 1, 4);  GQ(W18, 1, 8);  GQ(W19, 1, 12);
        GQ(W20, 1, 16); GQ(W21, 1, 20); GQ(W22, 1, 24); GQ(W23, 1, 28);
        GQ(W24, 1, 32);

        if (gth) {
            g_lds[0][slot][cell] = a0;
            g_lds[1][slot][cell] = a1;
            g_lds[2][slot][cell] = a2;
            g_lds[3][slot][cell] = a3;
        }
        __syncthreads();

        if (gth) {
            const float gi = g_lds[slot][0][cell];
            const float gf = g_lds[slot][1][cell];
            const float gg = g_lds[slot][2][cell];
            const float go = g_lds[slot][3][cell];
            cc = sigf(gf) * cc + sigf(gi) * tanhf_fast(gg);
            hh = sigf(go) * tanhf_fast(cc);
            h_lds[cur ^ 1][slot][cell] = hh;
        }
        __syncthreads();
    }
#undef GQ

    if (gth) hws[(size_t)(bbase + slot) * 300 + L * HID + cell] = hh;
}

// out[b][o] = relu(fc_b[o] + sum_j h[b][j] * fc_W[o][j]),  j < 300, o < 12
__global__ __launch_bounds__(64, 1) void fc_kernel(
    const float* __restrict__ hws, const float* __restrict__ fcW,
    const float* __restrict__ fcb, float* __restrict__ out)
{
    const int b = blockIdx.x, lane = threadIdx.x;
    float hv[5];
#pragma unroll
    for (int c = 0; c < 5; c++) {
        const int j = lane + 64 * c;
        hv[c] = (j < 300) ? hws[b * 300 + j] : 0.f;
    }
#pragma unroll
    for (int o = 0; o < 12; o++) {
        float a = 0.f;
#pragma unroll
        for (int c = 0; c < 5; c++) {
            const int j = lane + 64 * c;
            const float wv = (j < 300) ? fcW[o * 300 + j] : 0.f;
            a += hv[c] * wv;
        }
#pragma unroll
        for (int off = 32; off > 0; off >>= 1) a += __shfl_xor(a, off, 64);
        if (lane == 0) out[b * 12 + o] = fmaxf(a + fcb[o], 0.f);
    }
}

extern "C" void kernel_launch(void* const* d_in, const int* in_sizes, int n_in,
                              void* d_out, int out_size, void* d_ws, size_t ws_size,
                              hipStream_t stream)
{
    const float* x1   = (const float*)d_in[0];
    const float* x2   = (const float*)d_in[1];
    const float* x3   = (const float*)d_in[2];
    const float* Wih1 = (const float*)d_in[3];
    const float* Whh1 = (const float*)d_in[4];
    const float* bi1  = (const float*)d_in[5];
    const float* bh1  = (const float*)d_in[6];
    const float* Wih2 = (const float*)d_in[7];
    const float* Whh2 = (const float*)d_in[8];
    const float* bi2  = (const float*)d_in[9];
    const float* bh2  = (const float*)d_in[10];
    const float* Wih3 = (const float*)d_in[11];
    const float* Whh3 = (const float*)d_in[12];
    const float* bi3  = (const float*)d_in[13];
    const float* bh3  = (const float*)d_in[14];
    const float* fcW  = (const float*)d_in[15];
    const float* fcb  = (const float*)d_in[16];

    float* hws = (float*)d_ws;  // 256*300 floats = 300 KiB

    lstm3_kernel<<<3 * WPL, NTHR, 0, stream>>>(x1, x2, x3,
                                               Wih1, Whh1, bi1, bh1,
                                               Wih2, Whh2, bi2, bh2,
                                               Wih3, Whh3, bi3, bh3, hws);
    fc_kernel<<<256, 64, 0, stream>>>(hws, fcW, fcb, (float*)d_out);
}

// Round 8
// 2147.673 us; speedup vs baseline: 2.9586x; 2.8542x over previous
//
#include <hip/hip_runtime.h>

#define HID  100
#define TT   1024
#define BPW  16    // batches per WG (= MFMA N)
#define WPL  16    // WGs per LSTM -> grid 48
#define NTHR 512
#define KP   136   // padded K row length (f16 elems); 272B stride -> 2-way banks (free)
#define NROW 400
#define CHUNK 64   // x staging chunk (steps)

typedef _Float16 f16x4 __attribute__((ext_vector_type(4)));
typedef float    f32x4 __attribute__((ext_vector_type(4)));

__device__ __forceinline__ float sigf(float x) { return 1.f / (1.f + __expf(-x)); }
__device__ __forceinline__ float tanhf_fast(float x) { return 2.f / (1.f + __expf(-2.f * x)) - 1.f; }

#define MFMA16(A, B, C) __builtin_amdgcn_mfma_f32_16x16x16f16((A), (B), (C), 0, 0, 0)

// v7-MFMA: gates = W_aug x h_aug via v_mfma_f32_16x16x16f16.
//  - K-dims: [h(0..99) | x_t(100..103) | bias_hi(104) | bias_lo(105) | 0-pad],
//    so x-projection and bias ride inside the GEMM (B rows 104/105 hold 1.0).
//  - W rows permuted at staging so D reg r = gate r (i,f,g,o) of cell
//    4*tile + (lane>>4), batch = lane&15: cell update is pure per-lane math,
//    no shuffles, no gate LDS, ONE barrier per step.
//  - Precision: W/x/bias fp16 hi+lo columns; h split hi+lo (2 MFMAs into the
//    same fp32 acc) -> ~1e-4 end error.
//  - LDS/step: 200 W-frag b64 + 128 h-frag b64 ~ 1370 clk vs R3's 6400.
__global__ __launch_bounds__(NTHR) void lstm3_kernel(
    const float* __restrict__ x1, const float* __restrict__ x2, const float* __restrict__ x3,
    const float* __restrict__ Wih1, const float* __restrict__ Whh1, const float* __restrict__ bi1, const float* __restrict__ bh1,
    const float* __restrict__ Wih2, const float* __restrict__ Whh2, const float* __restrict__ bi2, const float* __restrict__ bh2,
    const float* __restrict__ Wih3, const float* __restrict__ Whh3, const float* __restrict__ bi3, const float* __restrict__ bh3,
    float* __restrict__ hws)
{
    const int wg    = blockIdx.x;
    const int L     = wg / WPL;
    const int bbase = (wg % WPL) * BPW;
    const int tid   = threadIdx.x;

    const float* x   = (L == 0) ? x1   : (L == 1) ? x2   : x3;
    const float* Wih = (L == 0) ? Wih1 : (L == 1) ? Wih2 : Wih3;
    const float* Whh = (L == 0) ? Whh1 : (L == 1) ? Whh2 : Whh3;
    const float* bi  = (L == 0) ? bi1  : (L == 1) ? bi2  : bi3;
    const float* bh  = (L == 0) ? bh1  : (L == 1) ? bh2  : bh3;

    __shared__ _Float16 Wl[NROW * KP];            // 108,800 B (permuted, fp16)
    __shared__ _Float16 hbf[2][2][BPW][KP];       //  17,408 B (buf, hi/lo, batch, k)
    __shared__ float    xch[2][BPW][CHUNK][4];    //  32,768 B (x chunks)

    // ---- one-time W staging (permuted rows + x-proj + bias hi/lo columns) ----
    for (int i = tid; i < NROW * KP; i += NTHR) {
        const int lr = i / KP, k = i % KP;
        const int t = lr >> 4, m = lr & 15;
        const int srow = (m & 3) * 100 + 4 * t + (m >> 2);  // gate=(m&3), cell=4t+(m>>2)
        float v = 0.f;
        if (k < 100)       v = Whh[srow * HID + k];
        else if (k < 104)  v = Wih[srow * 4 + (k - 100)];
        else if (k == 104) v = bi[srow] + bh[srow];
        else if (k == 105) { const float bv = bi[srow] + bh[srow];
                             v = bv - (float)(_Float16)bv; }
        Wl[i] = (_Float16)v;
    }
    // zero h buffers (h_0 = 0), then bias-lane columns = 1.0
    for (int i = tid; i < 2 * 2 * BPW * KP; i += NTHR) ((_Float16*)hbf)[i] = (_Float16)0.f;
    // x chunk 0
    for (int i = tid; i < BPW * CHUNK; i += NTHR) {
        const int b = i >> 6, s = i & 63;
        *(f32x4*)&xch[0][b][s][0] = *(const f32x4*)(x + ((size_t)(bbase + b) * TT + s) * 4);
    }
    __syncthreads();
    if (tid < 64) {  // hbf[buf][HI][b][104]=1, [105]=1  (2 bufs x 16 b x 2 cols)
        const int buf = tid >> 5, b = tid & 15, kc = 104 + ((tid >> 4) & 1);
        hbf[buf][0][b][kc] = (_Float16)1.f;
    }
    if (tid < 64) {  // x_0 -> hbf[0] rows 100..103 (hi/lo)
        const int b = tid & 15, d = tid >> 4;
        const float xv = x[((size_t)(bbase + b) * TT + 0) * 4 + d];
        const _Float16 hi = (_Float16)xv;
        hbf[0][0][b][100 + d] = hi;
        hbf[0][1][b][100 + d] = (_Float16)(xv - (float)hi);
    }
    __syncthreads();

    const int wave = tid >> 6, lane = tid & 63;
    const int bat = lane & 15, g16 = lane >> 4;   // batch (B/D col), quad group
    const int t0 = wave * 3, t1 = t0 + 1, t2 = t0 + 2;

    const _Float16* w0b = &Wl[(t0 * 16 + bat) * KP];  // A row m = lane&15
    const _Float16* w1b = &Wl[(t1 * 16 + bat) * KP];
    const _Float16* w2b = &Wl[(t2 * 16 + bat) * KP];
    const _Float16* w3b = &Wl[(24 * 16 + bat) * KP];  // wave 0 only
    const _Float16* hH0 = &hbf[0][0][bat][0];
    const _Float16* hL0 = &hbf[0][1][bat][0];
    const _Float16* hH1 = &hbf[1][0][bat][0];
    const _Float16* hL1 = &hbf[1][1][bat][0];

    float c0 = 0.f, c1 = 0.f, c2 = 0.f, c3 = 0.f;
    float h0 = 0.f, h1 = 0.f, h2 = 0.f, h3 = 0.f;

#pragma unroll 1
    for (int st = 0; st < TT; ++st) {
        const int cur = st & 1, nxt = cur ^ 1;
        const _Float16* hrH = cur ? hH1 : hH0;
        const _Float16* hrL = cur ? hL1 : hL0;

        f32x4 A0 = {0.f, 0.f, 0.f, 0.f}, A1 = A0, A2 = A0, A3 = A0;
#pragma unroll
        for (int kk = 0; kk < 8; ++kk) {
            const int ko = kk * 16 + g16 * 4;     // k = 16kk + 4*(lane>>4) + r
            const f16x4 bhi = *(const f16x4*)(hrH + ko);
            const f16x4 blo = *(const f16x4*)(hrL + ko);
            const f16x4 wf0 = *(const f16x4*)(w0b + ko);
            const f16x4 wf1 = *(const f16x4*)(w1b + ko);
            const f16x4 wf2 = *(const f16x4*)(w2b + ko);
            A0 = MFMA16(wf0, bhi, A0);  A0 = MFMA16(wf0, blo, A0);
            A1 = MFMA16(wf1, bhi, A1);  A1 = MFMA16(wf1, blo, A1);
            A2 = MFMA16(wf2, bhi, A2);  A2 = MFMA16(wf2, blo, A2);
            if (wave == 0) {
                const f16x4 wf3 = *(const f16x4*)(w3b + ko);
                A3 = MFMA16(wf3, bhi, A3);  A3 = MFMA16(wf3, blo, A3);
            }
        }

        // ---- cell update: lane owns (batch=bat, cell=4t+g16), gates in regs ----
        _Float16* dH = nxt ? (_Float16*)hH1 : (_Float16*)hH0;
        _Float16* dL = nxt ? (_Float16*)hL1 : (_Float16*)hL0;
#define UPD(AV, CS, HS, TI) do {                                              \
            CS = sigf(AV[1]) * CS + sigf(AV[0]) * tanhf_fast(AV[2]);          \
            HS = sigf(AV[3]) * tanhf_fast(CS);                                \
            const _Float16 hih = (_Float16)HS;                                \
            dH[4 * (TI) + g16] = hih;                                         \
            dL[4 * (TI) + g16] = (_Float16)(HS - (float)hih);                 \
        } while (0)
        UPD(A0, c0, h0, t0);
        UPD(A1, c1, h1, t1);
        UPD(A2, c2, h2, t2);
        if (wave == 0) UPD(A3, c3, h3, 24);
#undef UPD

        // ---- x for step st+1 (wave 7), from staged chunk ----
        if (wave == 7) {
            const int sp = (st + 1) & (TT - 1);
            const float xv = xch[(sp >> 6) & 1][bat][sp & 63][g16 & 3];
            const _Float16 hix = (_Float16)xv;
            dH[100 + (g16 & 3)] = hix;
            dL[100 + (g16 & 3)] = (_Float16)(xv - (float)hix);
        }
        // ---- prefetch next x chunk every 64 steps ----
        if ((st & 63) == 0) {
            const int nc = (st >> 6) + 1;
            if (nc < TT / CHUNK) {
                for (int i = tid; i < BPW * CHUNK; i += NTHR) {
                    const int b = i >> 6, s = i & 63;
                    *(f32x4*)&xch[nc & 1][b][s][0] =
                        *(const f32x4*)(x + ((size_t)(bbase + b) * TT + nc * CHUNK + s) * 4);
                }
            }
        }
        __syncthreads();
    }

    // final h -> workspace [b_global][300], column L*100 + cell
    {
        const size_t ob = (size_t)(bbase + bat) * 300 + L * HID;
        hws[ob + 4 * t0 + g16] = h0;
        hws[ob + 4 * t1 + g16] = h1;
        hws[ob + 4 * t2 + g16] = h2;
        if (wave == 0) hws[ob + 4 * 24 + g16] = h3;
    }
}

// out[b][o] = relu(fc_b[o] + sum_j h[b][j] * fc_W[o][j]),  j < 300, o < 12
__global__ __launch_bounds__(64, 1) void fc_kernel(
    const float* __restrict__ hws, const float* __restrict__ fcW,
    const float* __restrict__ fcb, float* __restrict__ out)
{
    const int b = blockIdx.x, lane = threadIdx.x;
    float hv[5];
#pragma unroll
    for (int c = 0; c < 5; c++) {
        const int j = lane + 64 * c;
        hv[c] = (j < 300) ? hws[b * 300 + j] : 0.f;
    }
#pragma unroll
    for (int o = 0; o < 12; o++) {
        float a = 0.f;
#pragma unroll
        for (int c = 0; c < 5; c++) {
            const int j = lane + 64 * c;
            const float wv = (j < 300) ? fcW[o * 300 + j] : 0.f;
            a += hv[c] * wv;
        }
#pragma unroll
        for (int off = 32; off > 0; off >>= 1) a += __shfl_xor(a, off, 64);
        if (lane == 0) out[b * 12 + o] = fmaxf(a + fcb[o], 0.f);
    }
}

extern "C" void kernel_launch(void* const* d_in, const int* in_sizes, int n_in,
                              void* d_out, int out_size, void* d_ws, size_t ws_size,
                              hipStream_t stream)
{
    const float* x1   = (const float*)d_in[0];
    const float* x2   = (const float*)d_in[1];
    const float* x3   = (const float*)d_in[2];
    const float* Wih1 = (const float*)d_in[3];
    const float* Whh1 = (const float*)d_in[4];
    const float* bi1  = (const float*)d_in[5];
    const float* bh1  = (const float*)d_in[6];
    const float* Wih2 = (const float*)d_in[7];
    const float* Whh2 = (const float*)d_in[8];
    const float* bi2  = (const float*)d_in[9];
    const float* bh2  = (const float*)d_in[10];
    const float* Wih3 = (const float*)d_in[11];
    const float* Whh3 = (const float*)d_in[12];
    const float* bi3  = (const float*)d_in[13];
    const float* bh3  = (const float*)d_in[14];
    const float* fcW  = (const float*)d_in[15];
    const float* fcb  = (const float*)d_in[16];

    float* hws = (float*)d_ws;  // 256*300 floats = 300 KiB

    lstm3_kernel<<<3 * WPL, NTHR, 0, stream>>>(x1, x2, x3,
                                               Wih1, Whh1, bi1, bh1,
                                               Wih2, Whh2, bi2, bh2,
                                               Wih3, Whh3, bi3, bh3, hws);
    fc_kernel<<<256, 64, 0, stream>>>(hws, fcW, fcb, (float*)d_out);
}

// Round 9
// 1811.682 us; speedup vs baseline: 3.5073x; 1.1855x over previous
//
#include <hip/hip_runtime.h>

#define HID  100
#define TT   1024
#define BPW  16    // batches per WG (= MFMA N)
#define WPL  16    // WGs per LSTM -> grid 48
#define NTHR 1024  // 16 waves
#define NKK  7     // K = 112: h(100) | x(4) | bias_hi,lo(2) | pad(6)

typedef _Float16 f16x4 __attribute__((ext_vector_type(4)));
typedef float    f32x4 __attribute__((ext_vector_type(4)));

__device__ __forceinline__ float sigf(float x) { return 1.f / (1.f + __expf(-x)); }
__device__ __forceinline__ float tanhf_fast(float x) { return 2.f / (1.f + __expf(-2.f * x)) - 1.f; }

#define MFMA16(A, B, C) __builtin_amdgcn_mfma_f32_16x16x16f16((A), (B), (C), 0, 0, 0)

// v8: R7's verified MFMA math, fragment-order LDS layout (zero bank conflicts),
// W fragments register-resident (28 VGPR/wave).
//  - Wfq[(t*7+kk)*64+lane] / hfq[buf][hl][kk][lane]: gate-phase reads are
//    LINEAR ds_read_b64 -> conflict-free (R7's stride-136 layout was 4-way,
//    6.6M conflict cycles/dispatch).
//  - waves 0..11: tiles {2w,2w+1}; wave 12: tile 24; wave 13: x-chunk
//    prefetch (16 KB / 64 steps); wave 15: x hi/lo insert for step st+1.
//  - one barrier per step (update writes hfq[nxt], reads were from hfq[cur]).
__global__ __launch_bounds__(NTHR, 1) void lstm3_kernel(
    const float* __restrict__ x1, const float* __restrict__ x2, const float* __restrict__ x3,
    const float* __restrict__ Wih1, const float* __restrict__ Whh1, const float* __restrict__ bi1, const float* __restrict__ bh1,
    const float* __restrict__ Wih2, const float* __restrict__ Whh2, const float* __restrict__ bi2, const float* __restrict__ bh2,
    const float* __restrict__ Wih3, const float* __restrict__ Whh3, const float* __restrict__ bi3, const float* __restrict__ bh3,
    float* __restrict__ hws)
{
    const int wg    = blockIdx.x;
    const int L     = wg / WPL;
    const int bbase = (wg % WPL) * BPW;
    const int tid   = threadIdx.x;

    const float* x   = (L == 0) ? x1   : (L == 1) ? x2   : x3;
    const float* Wih = (L == 0) ? Wih1 : (L == 1) ? Wih2 : Wih3;
    const float* Whh = (L == 0) ? Whh1 : (L == 1) ? Whh2 : Whh3;
    const float* bi  = (L == 0) ? bi1  : (L == 1) ? bi2  : bi3;
    const float* bh  = (L == 0) ? bh1  : (L == 1) ? bh2  : bh3;

    __shared__ f16x4 Wfq[25 * NKK * 64];      // 89,600 B  (fragment order)
    __shared__ f16x4 hfq[2][2][NKK][64];      // 14,336 B  (buf, hi/lo, kk, lane)
    __shared__ f32x4 xch[2][64][BPW];         // 32,768 B  (chunk, step, batch)

    // ---- one-time W staging in fragment order ----
    for (int idx = tid; idx < 25 * NKK * 64; idx += NTHR) {
        const int l   = idx & 63;
        const int kkt = idx >> 6;
        const int kk  = kkt % NKK, t = kkt / NKK;
        const int m   = l & 15, gq = l >> 4;
        const int k   = kk * 16 + gq * 4;
        const int srow = (m & 3) * 100 + 4 * t + (m >> 2);
        f16x4 q = {(_Float16)0.f, (_Float16)0.f, (_Float16)0.f, (_Float16)0.f};
        if (k < 100) {           // k multiple of 4, k+3 <= 99
            const f32x4 v = *(const f32x4*)(Whh + (size_t)srow * HID + k);
            q[0] = (_Float16)v[0]; q[1] = (_Float16)v[1];
            q[2] = (_Float16)v[2]; q[3] = (_Float16)v[3];
        } else if (k == 100) {   // Wih row
            const f32x4 v = *(const f32x4*)(Wih + (size_t)srow * 4);
            q[0] = (_Float16)v[0]; q[1] = (_Float16)v[1];
            q[2] = (_Float16)v[2]; q[3] = (_Float16)v[3];
        } else if (k == 104) {   // bias hi (j=0) / lo (j=1)
            const float bv = bi[srow] + bh[srow];
            const _Float16 hi = (_Float16)bv;
            q[0] = hi; q[1] = (_Float16)(bv - (float)hi);
        }
        Wfq[idx] = q;
    }
    // ---- h buffers: zero, then bias columns = 1.0, then x_0 ----
    for (int i = tid; i < 2 * 2 * NKK * 64; i += NTHR)
        ((f16x4*)hfq)[i] = (f16x4){(_Float16)0.f, (_Float16)0.f, (_Float16)0.f, (_Float16)0.f};
    // ---- x chunk 0 (step-major) ----
    for (int q = tid; q < 64 * BPW; q += NTHR) {
        const int s = q >> 4, b = q & 15;
        xch[0][s][b] = *(const f32x4*)(x + ((size_t)(bbase + b) * TT + s) * 4);
    }
    __syncthreads();
    if (tid < 32) {  // bias: k=104,105 -> kk=6, lane 32+bat, j=0,1 (both bufs, hi only)
        const int buf = tid >> 4, b = tid & 15;
        _Float16* p = (_Float16*)&hfq[buf][0][6][32 + b];
        p[0] = (_Float16)1.f; p[1] = (_Float16)1.f;
    }
    if (tid < 16) {  // x_0: kk=6, lane 16+bat, hi/lo quads (buf 0)
        const int b = tid;
        const f32x4 xv = xch[0][0][b];
        f16x4 hi, lo;
#pragma unroll
        for (int j = 0; j < 4; ++j) {
            hi[j] = (_Float16)xv[j];
            lo[j] = (_Float16)(xv[j] - (float)hi[j]);
        }
        hfq[0][0][6][16 + b] = hi;
        hfq[0][1][6][16 + b] = lo;
    }
    __syncthreads();

    const int wave = tid >> 6, lane = tid & 63;
    const int bat  = lane & 15, g16 = lane >> 4;

    const bool gw = wave < 13;                 // gate/update wave
    const bool vB = wave < 12;                 // slot B valid
    const int  tA = min(2 * wave, 24);
    const int  tB = min(2 * wave + 1, 24);

    // ---- W fragments -> registers (28 VGPRs/wave) ----
    const f16x4* wbA = &Wfq[(tA * NKK) * 64 + lane];
    const f16x4* wbB = &Wfq[(tB * NKK) * 64 + lane];
    f16x4 WA0 = wbA[0*64], WA1 = wbA[1*64], WA2 = wbA[2*64], WA3 = wbA[3*64],
          WA4 = wbA[4*64], WA5 = wbA[5*64], WA6 = wbA[6*64];
    f16x4 WB0 = wbB[0*64], WB1 = wbB[1*64], WB2 = wbB[2*64], WB3 = wbB[3*64],
          WB4 = wbB[4*64], WB5 = wbB[5*64], WB6 = wbB[6*64];
    asm volatile("" : "+v"(WA0), "+v"(WA1), "+v"(WA2), "+v"(WA3), "+v"(WA4));
    asm volatile("" : "+v"(WA5), "+v"(WA6), "+v"(WB0), "+v"(WB1), "+v"(WB2));
    asm volatile("" : "+v"(WB3), "+v"(WB4), "+v"(WB5), "+v"(WB6));

    float cc0 = 0.f, cc1 = 0.f, hh0 = 0.f, hh1 = 0.f;

#define KSTEP(KK, WA, WB) do {                                        \
        const f16x4 bhi = hb[(KK) * 64];                              \
        const f16x4 blo = hb[NKK * 64 + (KK) * 64];                   \
        A0 = MFMA16(WA, bhi, A0);                                     \
        A0 = MFMA16(WA, blo, A0);                                     \
        if (vB) { A1 = MFMA16(WB, bhi, A1); A1 = MFMA16(WB, blo, A1); } \
    } while (0)

#pragma unroll 1
    for (int st = 0; st < TT; ++st) {
        const int cur = st & 1, nxt = cur ^ 1;

        if (gw) {
            const f16x4* hb = &hfq[cur][0][0][lane];
            f32x4 A0 = {0.f, 0.f, 0.f, 0.f}, A1 = {0.f, 0.f, 0.f, 0.f};
            KSTEP(0, WA0, WB0); KSTEP(1, WA1, WB1); KSTEP(2, WA2, WB2);
            KSTEP(3, WA3, WB3); KSTEP(4, WA4, WB4); KSTEP(5, WA5, WB5);
            KSTEP(6, WA6, WB6);

            // ---- update: lane owns (bat, cell=4t+g16); gates = regs r=0..3 ----
            {
                cc0 = sigf(A0[1]) * cc0 + sigf(A0[0]) * tanhf_fast(A0[2]);
                hh0 = sigf(A0[3]) * tanhf_fast(cc0);
                const _Float16 hi = (_Float16)hh0;
                const _Float16 lo = (_Float16)(hh0 - (float)hi);
                _Float16* pH = (_Float16*)&hfq[nxt][0][tA >> 2][(tA & 3) * 16 + bat];
                _Float16* pL = (_Float16*)&hfq[nxt][1][tA >> 2][(tA & 3) * 16 + bat];
                pH[g16] = hi; pL[g16] = lo;
            }
            if (vB) {
                cc1 = sigf(A1[1]) * cc1 + sigf(A1[0]) * tanhf_fast(A1[2]);
                hh1 = sigf(A1[3]) * tanhf_fast(cc1);
                const _Float16 hi = (_Float16)hh1;
                const _Float16 lo = (_Float16)(hh1 - (float)hi);
                _Float16* pH = (_Float16*)&hfq[nxt][0][tB >> 2][(tB & 3) * 16 + bat];
                _Float16* pL = (_Float16*)&hfq[nxt][1][tB >> 2][(tB & 3) * 16 + bat];
                pH[g16] = hi; pL[g16] = lo;
            }
        } else if (wave == 15) {
            if (lane < 16) {   // x_{st+1} -> hfq[nxt] (kk=6, lane 16+bat)
                const int sp = st + 1;
                const f32x4 xv = xch[(sp >> 6) & 1][sp & 63][lane];
                f16x4 hi, lo;
#pragma unroll
                for (int j = 0; j < 4; ++j) {
                    hi[j] = (_Float16)xv[j];
                    lo[j] = (_Float16)(xv[j] - (float)hi[j]);
                }
                hfq[nxt][0][6][16 + lane] = hi;
                hfq[nxt][1][6][16 + lane] = lo;
            }
        } else if (wave == 13) {
            if ((st & 63) == 0) {   // prefetch next 64-step x chunk
                const int nc = (st >> 6) + 1;
                if (nc < TT / 64) {
#pragma unroll
                    for (int it = 0; it < 16; ++it) {
                        const int q = it * 64 + lane;
                        const int s = q >> 4, b = q & 15;
                        xch[nc & 1][s][b] =
                            *(const f32x4*)(x + ((size_t)(bbase + b) * TT + nc * 64 + s) * 4);
                    }
                }
            }
        }
        __syncthreads();
    }
#undef KSTEP

    // ---- final h -> workspace [b_global][300], column L*100 + cell ----
    if (gw) {
        const size_t ob = (size_t)(bbase + bat) * 300 + L * HID;
        hws[ob + 4 * tA + g16] = hh0;
        if (vB) hws[ob + 4 * tB + g16] = hh1;
    }
}

// out[b][o] = relu(fc_b[o] + sum_j h[b][j] * fc_W[o][j]),  j < 300, o < 12
__global__ __launch_bounds__(64, 1) void fc_kernel(
    const float* __restrict__ hws, const float* __restrict__ fcW,
    const float* __restrict__ fcb, float* __restrict__ out)
{
    const int b = blockIdx.x, lane = threadIdx.x;
    float hv[5];
#pragma unroll
    for (int c = 0; c < 5; c++) {
        const int j = lane + 64 * c;
        hv[c] = (j < 300) ? hws[b * 300 + j] : 0.f;
    }
#pragma unroll
    for (int o = 0; o < 12; o++) {
        float a = 0.f;
#pragma unroll
        for (int c = 0; c < 5; c++) {
            const int j = lane + 64 * c;
            const float wv = (j < 300) ? fcW[o * 300 + j] : 0.f;
            a += hv[c] * wv;
        }
#pragma unroll
        for (int off = 32; off > 0; off >>= 1) a += __shfl_xor(a, off, 64);
        if (lane == 0) out[b * 12 + o] = fmaxf(a + fcb[o], 0.f);
    }
}

extern "C" void kernel_launch(void* const* d_in, const int* in_sizes, int n_in,
                              void* d_out, int out_size, void* d_ws, size_t ws_size,
                              hipStream_t stream)
{
    const float* x1   = (const float*)d_in[0];
    const float* x2   = (const float*)d_in[1];
    const float* x3   = (const float*)d_in[2];
    const float* Wih1 = (const float*)d_in[3];
    const float* Whh1 = (const float*)d_in[4];
    const float* bi1  = (const float*)d_in[5];
    const float* bh1  = (const float*)d_in[6];
    const float* Wih2 = (const float*)d_in[7];
    const float* Whh2 = (const float*)d_in[8];
    const float* bi2  = (const float*)d_in[9];
    const float* bh2  = (const float*)d_in[10];
    const float* Wih3 = (const float*)d_in[11];
    const float* Whh3 = (const float*)d_in[12];
    const float* bi3  = (const float*)d_in[13];
    const float* bh3  = (const float*)d_in[14];
    const float* fcW  = (const float*)d_in[15];
    const float* fcb  = (const float*)d_in[16];

    float* hws = (float*)d_ws;  // 256*300 floats = 300 KiB

    lstm3_kernel<<<3 * WPL, NTHR, 0, stream>>>(x1, x2, x3,
                                               Wih1, Whh1, bi1, bh1,
                                               Wih2, Whh2, bi2, bh2,
                                               Wih3, Whh3, bi3, bh3, hws);
    fc_kernel<<<256, 64, 0, stream>>>(hws, fcW, fcb, (float*)d_out);
}

// Round 10
// 1616.061 us; speedup vs baseline: 3.9318x; 1.1210x over previous
//
#include <hip/hip_runtime.h>

#define HID  100
#define TT   1024
#define BPW  16    // batches per WG (= MFMA N)
#define WPL  16    // WGs per LSTM -> grid 48
#define NTHR 1024  // 16 waves
#define NKK  4     // K = 128: 4 chunks of 32

typedef _Float16 f16x8 __attribute__((ext_vector_type(8)));
typedef float    f32x4 __attribute__((ext_vector_type(4)));

__device__ __forceinline__ float sigf(float x) { return 1.f / (1.f + __expf(-x)); }
__device__ __forceinline__ float tanhf_fast(float x) { return 2.f / (1.f + __expf(-2.f * x)) - 1.f; }

#define MFMA32(A, B, C) __builtin_amdgcn_mfma_f32_16x16x32_f16((A), (B), (C), 0, 0, 0)

// v9: R8's verified structure, K=32 MFMA (gfx950 2xK) + separate hi/lo accs.
//  - Slot->k convention (ke = kk*32 + g*8 + j) applied consistently to BOTH
//    A (W) and B (h) fragments: dot products are permutation-invariant, so
//    the HW's internal k-interleave is irrelevant; only the (verified) C/D
//    layout matters.
//  - MFMA/WG/step 350 -> 200; dependent-chain length 14 -> 4 (x4 independent
//    chains/wave); ds_read instrs/wave 14 b64 -> 8 b128.
//  - K-dims: h(0..99) | x(100..103) | bias_hi(104) | bias_lo(105) | 0-pad.
__global__ __launch_bounds__(NTHR, 1) void lstm3_kernel(
    const float* __restrict__ x1, const float* __restrict__ x2, const float* __restrict__ x3,
    const float* __restrict__ Wih1, const float* __restrict__ Whh1, const float* __restrict__ bi1, const float* __restrict__ bh1,
    const float* __restrict__ Wih2, const float* __restrict__ Whh2, const float* __restrict__ bi2, const float* __restrict__ bh2,
    const float* __restrict__ Wih3, const float* __restrict__ Whh3, const float* __restrict__ bi3, const float* __restrict__ bh3,
    float* __restrict__ hws)
{
    const int wg    = blockIdx.x;
    const int L     = wg / WPL;
    const int bbase = (wg % WPL) * BPW;
    const int tid   = threadIdx.x;

    const float* x   = (L == 0) ? x1   : (L == 1) ? x2   : x3;
    const float* Wih = (L == 0) ? Wih1 : (L == 1) ? Wih2 : Wih3;
    const float* Whh = (L == 0) ? Whh1 : (L == 1) ? Whh2 : Whh3;
    const float* bi  = (L == 0) ? bi1  : (L == 1) ? bi2  : bi3;
    const float* bh  = (L == 0) ? bh1  : (L == 1) ? bh2  : bh3;

    __shared__ f16x8 Wfq[25 * NKK * 64];      // 102,400 B (fragment order)
    __shared__ f16x8 hfq[2][2][NKK][64];      //  16,384 B (buf, hi/lo, kk, lane)
    __shared__ f32x4 xch[2][64][BPW];         //  32,768 B -> total 151,552 B

    // ---- one-time W staging in fragment order (slot->k: ke = kk*32+g*8+j) ----
    for (int idx = tid; idx < 25 * NKK * 64; idx += NTHR) {
        const int l   = idx & 63;
        const int kkt = idx >> 6;
        const int kk  = kkt & 3, t = kkt >> 2;
        const int m   = l & 15, g = l >> 4;
        const int srow = (m & 3) * 100 + 4 * t + (m >> 2);
        f16x8 q;
#pragma unroll
        for (int j = 0; j < 8; ++j) {
            const int ke = kk * 32 + g * 8 + j;
            float v = 0.f;
            if (ke < 100)       v = Whh[(size_t)srow * HID + ke];
            else if (ke < 104)  v = Wih[(size_t)srow * 4 + (ke - 100)];
            else if (ke == 104) v = bi[srow] + bh[srow];
            else if (ke == 105) { const float bv = bi[srow] + bh[srow];
                                  v = bv - (float)(_Float16)bv; }
            q[j] = (_Float16)v;
        }
        Wfq[idx] = q;
    }
    // ---- h buffers zero ----
    for (int i = tid; i < 2 * 2 * NKK * 64; i += NTHR) {
        f16x8 z;
#pragma unroll
        for (int j = 0; j < 8; ++j) z[j] = (_Float16)0.f;
        ((f16x8*)hfq)[i] = z;
    }
    // ---- x chunk 0 (step-major) ----
    for (int q = tid; q < 64 * BPW; q += NTHR) {
        const int s = q >> 4, b = q & 15;
        xch[0][s][b] = *(const f32x4*)(x + ((size_t)(bbase + b) * TT + s) * 4);
    }
    __syncthreads();
    if (tid < 32) {  // bias columns ke=104,105 -> kk=3, g=1, j=0,1 (hi, both bufs)
        const int buf = tid >> 4, b = tid & 15;
        _Float16* p = (_Float16*)&hfq[buf][0][3][16 + b];
        p[0] = (_Float16)1.f; p[1] = (_Float16)1.f;
    }
    if (tid < 16) {  // x_0: ke=100..103 -> kk=3, g=0, j=4..7 (buf 0)
        const int b = tid;
        const f32x4 xv = xch[0][0][b];
        _Float16* pH = (_Float16*)&hfq[0][0][3][b];
        _Float16* pL = (_Float16*)&hfq[0][1][3][b];
#pragma unroll
        for (int j = 0; j < 4; ++j) {
            const _Float16 hi = (_Float16)xv[j];
            pH[4 + j] = hi;
            pL[4 + j] = (_Float16)(xv[j] - (float)hi);
        }
    }
    __syncthreads();

    const int wave = tid >> 6, lane = tid & 63;
    const int bat  = lane & 15, g16 = lane >> 4;

    const bool gw = wave < 13;                 // gate/update wave
    const bool vB = wave < 12;                 // slot B valid
    const int  tA = min(2 * wave, 24);
    const int  tB = min(2 * wave + 1, 24);

    // ---- W fragments -> registers (8 f16x8 = 32 VGPRs/wave) ----
    const f16x8* wbA = &Wfq[(tA * NKK) * 64 + lane];
    const f16x8* wbB = &Wfq[(tB * NKK) * 64 + lane];
    f16x8 WA0 = wbA[0*64], WA1 = wbA[1*64], WA2 = wbA[2*64], WA3 = wbA[3*64];
    f16x8 WB0 = wbB[0*64], WB1 = wbB[1*64], WB2 = wbB[2*64], WB3 = wbB[3*64];
    asm volatile("" : "+v"(WA0), "+v"(WA1), "+v"(WA2), "+v"(WA3));
    asm volatile("" : "+v"(WB0), "+v"(WB1), "+v"(WB2), "+v"(WB3));

    float cc0 = 0.f, cc1 = 0.f, hh0 = 0.f, hh1 = 0.f;

    // update-write mapping for cell c: kk=c>>5, word=((c&31)>>3)*16+bat, elem=c&7
    const int cA = 4 * tA + g16, cB = 4 * tB + g16;

#pragma unroll 1
    for (int st = 0; st < TT; ++st) {
        const int cur = st & 1, nxt = cur ^ 1;

        if (gw) {
            const f16x8* hb = &hfq[cur][0][0][lane];   // hi at [kk*64], lo at [NKK*64 + kk*64]
            f32x4 A0h = {0.f,0.f,0.f,0.f}, A0l = A0h, A1h = A0h, A1l = A0h;
            {
                const f16x8 bhi = hb[0*64], blo = hb[NKK*64 + 0*64];
                A0h = MFMA32(WA0, bhi, A0h);  A0l = MFMA32(WA0, blo, A0l);
                if (vB) { A1h = MFMA32(WB0, bhi, A1h);  A1l = MFMA32(WB0, blo, A1l); }
            }
            {
                const f16x8 bhi = hb[1*64], blo = hb[NKK*64 + 1*64];
                A0h = MFMA32(WA1, bhi, A0h);  A0l = MFMA32(WA1, blo, A0l);
                if (vB) { A1h = MFMA32(WB1, bhi, A1h);  A1l = MFMA32(WB1, blo, A1l); }
            }
            {
                const f16x8 bhi = hb[2*64], blo = hb[NKK*64 + 2*64];
                A0h = MFMA32(WA2, bhi, A0h);  A0l = MFMA32(WA2, blo, A0l);
                if (vB) { A1h = MFMA32(WB2, bhi, A1h);  A1l = MFMA32(WB2, blo, A1l); }
            }
            {
                const f16x8 bhi = hb[3*64], blo = hb[NKK*64 + 3*64];
                A0h = MFMA32(WA3, bhi, A0h);  A0l = MFMA32(WA3, blo, A0l);
                if (vB) { A1h = MFMA32(WB3, bhi, A1h);  A1l = MFMA32(WB3, blo, A1l); }
            }
            const f32x4 A0 = A0h + A0l;
            const f32x4 A1 = A1h + A1l;

            // ---- update: lane owns (bat, cell=4t+g16); gates = regs r=0..3 ----
            {
                cc0 = sigf(A0[1]) * cc0 + sigf(A0[0]) * tanhf_fast(A0[2]);
                hh0 = sigf(A0[3]) * tanhf_fast(cc0);
                const _Float16 hi = (_Float16)hh0;
                const _Float16 lo = (_Float16)(hh0 - (float)hi);
                _Float16* pH = (_Float16*)&hfq[nxt][0][cA >> 5][(((cA & 31) >> 3) << 4) + bat];
                _Float16* pL = (_Float16*)&hfq[nxt][1][cA >> 5][(((cA & 31) >> 3) << 4) + bat];
                pH[cA & 7] = hi; pL[cA & 7] = lo;
            }
            if (vB) {
                cc1 = sigf(A1[1]) * cc1 + sigf(A1[0]) * tanhf_fast(A1[2]);
                hh1 = sigf(A1[3]) * tanhf_fast(cc1);
                const _Float16 hi = (_Float16)hh1;
                const _Float16 lo = (_Float16)(hh1 - (float)hi);
                _Float16* pH = (_Float16*)&hfq[nxt][0][cB >> 5][(((cB & 31) >> 3) << 4) + bat];
                _Float16* pL = (_Float16*)&hfq[nxt][1][cB >> 5][(((cB & 31) >> 3) << 4) + bat];
                pH[cB & 7] = hi; pL[cB & 7] = lo;
            }
        } else if (wave == 15) {
            if (lane < 16) {   // x_{st+1}: ke=100..103 -> kk=3, g=0, j=4..7
                const int sp = st + 1;
                const f32x4 xv = xch[(sp >> 6) & 1][sp & 63][lane];
                _Float16* pH = (_Float16*)&hfq[nxt][0][3][lane];
                _Float16* pL = (_Float16*)&hfq[nxt][1][3][lane];
#pragma unroll
                for (int j = 0; j < 4; ++j) {
                    const _Float16 hi = (_Float16)xv[j];
                    pH[4 + j] = hi;
                    pL[4 + j] = (_Float16)(xv[j] - (float)hi);
                }
            }
        } else if (wave == 13) {
            if ((st & 63) == 0) {   // prefetch next 64-step x chunk
                const int nc = (st >> 6) + 1;
                if (nc < TT / 64) {
#pragma unroll
                    for (int it = 0; it < 16; ++it) {
                        const int q = it * 64 + lane;
                        const int s = q >> 4, b = q & 15;
                        xch[nc & 1][s][b] =
                            *(const f32x4*)(x + ((size_t)(bbase + b) * TT + nc * 64 + s) * 4);
                    }
                }
            }
        }
        __syncthreads();
    }

    // ---- final h -> workspace [b_global][300], column L*100 + cell ----
    if (gw) {
        const size_t ob = (size_t)(bbase + bat) * 300 + L * HID;
        hws[ob + cA] = hh0;
        if (vB) hws[ob + cB] = hh1;
    }
}

// out[b][o] = relu(fc_b[o] + sum_j h[b][j] * fc_W[o][j]),  j < 300, o < 12
__global__ __launch_bounds__(64, 1) void fc_kernel(
    const float* __restrict__ hws, const float* __restrict__ fcW,
    const float* __restrict__ fcb, float* __restrict__ out)
{
    const int b = blockIdx.x, lane = threadIdx.x;
    float hv[5];
#pragma unroll
    for (int c = 0; c < 5; c++) {
        const int j = lane + 64 * c;
        hv[c] = (j < 300) ? hws[b * 300 + j] : 0.f;
    }
#pragma unroll
    for (int o = 0; o < 12; o++) {
        float a = 0.f;
#pragma unroll
        for (int c = 0; c < 5; c++) {
            const int j = lane + 64 * c;
            const float wv = (j < 300) ? fcW[o * 300 + j] : 0.f;
            a += hv[c] * wv;
        }
#pragma unroll
        for (int off = 32; off > 0; off >>= 1) a += __shfl_xor(a, off, 64);
        if (lane == 0) out[b * 12 + o] = fmaxf(a + fcb[o], 0.f);
    }
}

extern "C" void kernel_launch(void* const* d_in, const int* in_sizes, int n_in,
                              void* d_out, int out_size, void* d_ws, size_t ws_size,
                              hipStream_t stream)
{
    const float* x1   = (const float*)d_in[0];
    const float* x2   = (const float*)d_in[1];
    const float* x3   = (const float*)d_in[2];
    const float* Wih1 = (const float*)d_in[3];
    const float* Whh1 = (const float*)d_in[4];
    const float* bi1  = (const float*)d_in[5];
    const float* bh1  = (const float*)d_in[6];
    const float* Wih2 = (const float*)d_in[7];
    const float* Whh2 = (const float*)d_in[8];
    const float* bi2  = (const float*)d_in[9];
    const float* bh2  = (const float*)d_in[10];
    const float* Wih3 = (const float*)d_in[11];
    const float* Whh3 = (const float*)d_in[12];
    const float* bi3  = (const float*)d_in[13];
    const float* bh3  = (const float*)d_in[14];
    const float* fcW  = (const float*)d_in[15];
    const float* fcb  = (const float*)d_in[16];

    float* hws = (float*)d_ws;  // 256*300 floats = 300 KiB

    lstm3_kernel<<<3 * WPL, NTHR, 0, stream>>>(x1, x2, x3,
                                               Wih1, Whh1, bi1, bh1,
                                               Wih2, Whh2, bi2, bh2,
                                               Wih3, Whh3, bi3, bh3, hws);
    fc_kernel<<<256, 64, 0, stream>>>(hws, fcW, fcb, (float*)d_out);
}